// Round 15
// baseline (630.728 us; speedup 1.0000x reference)
//
#include <hip/hip_runtime.h>

#define C_CH 16
#define Hdim 128
#define Wdim 128
#define HWdim 16384
#define CHW (C_CH * HWdim)                 // 262144 floats: one [C][H][W] slab
#define Bdim 2
#define PAIR_ELEMS (Bdim * CHW)            // 524288

// padded canvas geometry (border 3 = max P/2, zeroed once per launch)
#define HP 134
#define WP 136
#define PL (HP * WP)                       // 18224 elements per plane

typedef float v2f __attribute__((ext_vector_type(2)));
typedef _Float16 h2 __attribute__((ext_vector_type(2)));

__device__ __forceinline__ v2f unpack2(unsigned u) {
  h2 h = __builtin_bit_cast(h2, u);
  return (v2f){(float)h.x, (float)h.y};
}
__device__ __forceinline__ unsigned pack2(float a, float b) {
  h2 h = {(_Float16)a, (_Float16)b};
  return __builtin_bit_cast(unsigned, h);
}

__device__ __forceinline__ void gadd(float* p, float v) {
  __hip_atomic_fetch_add(p, v, __ATOMIC_RELAXED, __HIP_MEMORY_SCOPE_AGENT);
}

// conflict-free LDS row strides (elements):
//  8x8 reads:  SR % 8 == 4;  16x4 reads: SR % 32 in {8,16,24}
template<int P> struct SimSR { static constexpr int v = (P == 7) ? 20 : 12; };

// ---------------------------------------------------------------------------
// Prep: memT[d][m] = mem * temp/sqrt(D)   (f32, m-contiguous)
//       memR[m][u][v][c]                  (f32, kernel-flipped, c-contiguous)
// ---------------------------------------------------------------------------
struct PrepDesc {
  const float* mem;
  const float* temp;
  float* memT;
  float* memR;
  int M, D, P;
};
struct PrepArgs { PrepDesc d[6]; };

__global__ __launch_bounds__(256) void k_prep(PrepArgs a) {
  PrepDesc de = a.d[blockIdx.y];
  int n = de.M * de.D;
  int idx = blockIdx.x * 256 + threadIdx.x;
  if (idx >= n) return;
  int m = idx / de.D;
  int d = idx - m * de.D;
  float v = de.mem[idx];
  float sc = de.temp[0] / sqrtf((float)de.D);
  de.memT[d * de.M + m] = v * sc;
  int pp = de.P * de.P;
  int c = d / pp;
  int r = d - c * pp;
  int i = r / de.P;
  int j = r - i * de.P;
  de.memR[((m * de.P + (de.P - 1 - i)) * de.P + (de.P - 1 - j)) * C_CH + c] = v;
}

// ---------------------------------------------------------------------------
// Build f16 c-pair-packed padded canvas.
// ---------------------------------------------------------------------------
__global__ __launch_bounds__(256) void k_padx(const float* __restrict__ bg,
                                              const float* __restrict__ tg,
                                              unsigned* __restrict__ xpad2)
{
  int idx = blockIdx.x * 256 + threadIdx.x;     // 32 pair-planes * HW
  int pp = idx >> 14;
  int hw = idx & (HWdim - 1);
  int y = hw >> 7, x = hw & 127;
  int z = pp >> 3, cp = pp & 7;
  const float* src = (z < 2) ? bg : tg;
  int b = z & 1;
  float a = src[((b * C_CH + 2 * cp) << 14) + hw];
  float bb = src[((b * C_CH + 2 * cp + 1) << 14) + hw];
  xpad2[(size_t)pp * PL + (y + 3) * WP + (x + 3)] = pack2(a, bb);
}

// ---------------------------------------------------------------------------
// Sim conv + softmax -> att2 (m-pair-packed f16 padded planes).  [R11 form]
// 8x8 tile, 512 thr = 8 waves; one dispatch per scale (template P).
// ---------------------------------------------------------------------------
template<int P>
__device__ __forceinline__ void sim_core_bg(
    const unsigned* __restrict__ xt2, float* __restrict__ red,
    const float* __restrict__ memT, unsigned* __restrict__ att2,
    int wv, int lane, int x0, int y0)
{
  constexpr int TH = 8 + P - 1, SR = SimSR<P>::v;
  constexpr int M = 64;
  const int px = lane & 7, py = lane >> 3;
  const int m0 = wv * 8;
  v2f acc2[4];
#pragma unroll
  for (int mm = 0; mm < 4; ++mm) acc2[mm] = (v2f){0.f, 0.f};

  for (int cp = 0; cp < 8; ++cp) {
#pragma unroll
    for (int i = 0; i < P; ++i) {
#pragma unroll
      for (int j = 0; j < P; ++j) {
        v2f vp = unpack2(xt2[(cp * TH + py + i) * SR + (px + j)]);
        const v2f* w0 = (const v2f*)(memT + (size_t)((((2 * cp) * P + i) * P + j)) * M + m0);
        const v2f* w1 = (const v2f*)(memT + (size_t)((((2 * cp + 1) * P + i) * P + j)) * M + m0);
        v2f v0 = {vp.x, vp.x}, v1 = {vp.y, vp.y};
#pragma unroll
        for (int mm = 0; mm < 4; ++mm) {
          acc2[mm] = __builtin_elementwise_fma(v0, w0[mm], acc2[mm]);
          acc2[mm] = __builtin_elementwise_fma(v1, w1[mm], acc2[mm]);
        }
      }
    }
  }

  float acc[8];
#pragma unroll
  for (int mm = 0; mm < 4; ++mm) { acc[2 * mm] = acc2[mm].x; acc[2 * mm + 1] = acc2[mm].y; }

  float pm = acc[0];
#pragma unroll
  for (int mm = 1; mm < 8; ++mm) pm = fmaxf(pm, acc[mm]);
  red[wv * 64 + lane] = pm;
  __syncthreads();
  float gm = red[lane];
#pragma unroll
  for (int w = 1; w < 8; ++w) gm = fmaxf(gm, red[w * 64 + lane]);
  __syncthreads();
  float ps = 0.f;
#pragma unroll
  for (int mm = 0; mm < 8; ++mm) { acc[mm] = __expf(acc[mm] - gm); ps += acc[mm]; }
  red[wv * 64 + lane] = ps;
  __syncthreads();
  float tot = 0.f;
#pragma unroll
  for (int w = 0; w < 8; ++w) tot += red[w * 64 + lane];
  float inv = 1.f / tot;

  const int gy = y0 + py, gx = x0 + px;
#pragma unroll
  for (int k = 0; k < 4; ++k) {
    int mp = (m0 >> 1) + k;
    att2[(size_t)mp * PL + (gy + 3) * WP + (gx + 3)] =
        pack2(acc[2 * k] * inv, acc[2 * k + 1] * inv);
  }
}

template<int P>
__device__ __forceinline__ void sim_core_tg(
    const unsigned* __restrict__ xt2, float* __restrict__ red,  // [8][8][64]
    const float* __restrict__ memT, unsigned* __restrict__ att2,
    int wv, int lane, int x0, int y0)
{
  constexpr int TH = 8 + P - 1, SR = SimSR<P>::v;
  constexpr int M = 8;
  const int px = lane & 7, py = lane >> 3;
  const int cp = wv;
  v2f acc2[4];
#pragma unroll
  for (int mm = 0; mm < 4; ++mm) acc2[mm] = (v2f){0.f, 0.f};

#pragma unroll
  for (int i = 0; i < P; ++i) {
#pragma unroll
    for (int j = 0; j < P; ++j) {
      v2f vp = unpack2(xt2[(cp * TH + py + i) * SR + (px + j)]);
      const v2f* w0 = (const v2f*)(memT + (size_t)((((2 * cp) * P + i) * P + j)) * M);
      const v2f* w1 = (const v2f*)(memT + (size_t)((((2 * cp + 1) * P + i) * P + j)) * M);
      v2f v0 = {vp.x, vp.x}, v1 = {vp.y, vp.y};
#pragma unroll
      for (int mm = 0; mm < 4; ++mm) {
        acc2[mm] = __builtin_elementwise_fma(v0, w0[mm], acc2[mm]);
        acc2[mm] = __builtin_elementwise_fma(v1, w1[mm], acc2[mm]);
      }
    }
  }

#pragma unroll
  for (int mm = 0; mm < 4; ++mm) {
    red[(wv * 8 + 2 * mm) * 64 + lane]     = acc2[mm].x;
    red[(wv * 8 + 2 * mm + 1) * 64 + lane] = acc2[mm].y;
  }
  __syncthreads();

  float lg[8];
#pragma unroll
  for (int m = 0; m < 8; ++m) {
    float s = red[m * 64 + lane];
#pragma unroll
    for (int w = 1; w < 8; ++w) s += red[(w * 8 + m) * 64 + lane];
    lg[m] = s;
  }
  float gm = lg[0];
#pragma unroll
  for (int m = 1; m < 8; ++m) gm = fmaxf(gm, lg[m]);
  float tot = 0.f;
#pragma unroll
  for (int m = 0; m < 8; ++m) { lg[m] = __expf(lg[m] - gm); tot += lg[m]; }
  float inv = 1.f / tot;

  const int gy = y0 + py, gx = x0 + px;
  if (wv < 4)
    att2[(size_t)wv * PL + (gy + 3) * WP + (gx + 3)] =
        pack2(lg[2 * wv] * inv, lg[2 * wv + 1] * inv);
}

template<int P>
__global__ __launch_bounds__(512, 8) void k_sim(
    const unsigned* __restrict__ xpad2,
    const float* __restrict__ memTbg, const float* __restrict__ memTtg,
    unsigned* __restrict__ attbg2,   // [2][32] pair-planes
    unsigned* __restrict__ atttg2)   // [2][4]  pair-planes
{
  constexpr int PAD = P / 2, TH = 8 + P - 1, SR = SimSR<P>::v;
  __shared__ unsigned xt2[8 * TH * SR];
  __shared__ float red[8 * 8 * 64];

  const int tid = threadIdx.x;
  const int wv = __builtin_amdgcn_readfirstlane(tid >> 6);
  const int lane = tid & 63;
  const int x0 = blockIdx.x * 8, y0 = blockIdx.y * 8;
  const int z = blockIdx.z;
  const bool isbg = z < 2;
  const int b = z & 1;

  const unsigned* xp = xpad2 + (size_t)(z * 8) * PL;
  const int oy = y0 + 3 - PAD, ox = x0 + 3 - PAD;
  for (int t = tid; t < 8 * TH * TH; t += 512) {
    int cp = t / (TH * TH);
    int r = t - cp * (TH * TH);
    int ly = r / TH, lx = r - ly * TH;
    xt2[(cp * TH + ly) * SR + lx] = xp[(size_t)cp * PL + (oy + ly) * WP + ox + lx];
  }
  __syncthreads();

  if (isbg) sim_core_bg<P>(xt2, red, memTbg, attbg2 + (size_t)(b * 32) * PL, wv, lane, x0, y0);
  else      sim_core_tg<P>(xt2, red, memTtg, atttg2 + (size_t)(b * 4) * PL, wv, lane, x0, y0);
}

// ---------------------------------------------------------------------------
// Read conv (pipelined hybrid): 16x16 tile, 1 thread = 1 pixel, fp32 inner
// loop; f16 traffic. Staging is DOUBLE-BUFFERED per m-pair phase: issue
// phase k+1 global loads into regs, compute phase k from LDS buf k&1, then
// write regs to buf (k+1)&1 -> global latency overlaps compute.
// bg: 2 phases (chunk of 4 m); tg: 4 phases (8 m) -> fp32 final.
// z: 0,1 tg b; 2..33 bg chunk=(z-2)>>1, b=(z-2)&1.  SR=24 conflict-free.
// ---------------------------------------------------------------------------
template<int P>
__global__ __launch_bounds__(256, 8) void k_read(
    const unsigned* __restrict__ attbg2,   // [2][32] pair-planes
    const unsigned* __restrict__ atttg2,   // [2][4]  pair-planes
    const float* __restrict__ memRbg, const float* __restrict__ memRtg,
    unsigned* __restrict__ pbg2,           // [16][2][8][HW] u32 (this scale)
    float* __restrict__ ftg)               // [2 b][CHW]       (this scale)
{
  constexpr int PAD = P / 2, TH = 16 + P - 1, SR = 24;
  constexpr int BUF = 2 * TH * SR;         // one buffer: 2 fp32 planes
  __shared__ float atf[2 * BUF];

  const int tid = threadIdx.x;
  const int x0 = blockIdx.x * 16, y0 = blockIdx.y * 16;
  const int z = blockIdx.z;
  const bool isbg = z >= 2;
  const int b = isbg ? ((z - 2) & 1) : z;
  const int chunk = isbg ? ((z - 2) >> 1) : 0;
  const int nmp = isbg ? 2 : 4;            // m-pair phases
  const int mbase = isbg ? chunk * 4 : 0;
  const unsigned* attp = isbg ? (attbg2 + (size_t)(b * 32 + chunk * 2) * PL)
                              : (atttg2 + (size_t)(b * 4) * PL);
  const float* memR = isbg ? memRbg : memRtg;

  // staging geometry: TH*TH <= 484 < 512 -> 2 slots/thread
  const int oy = y0 + 3 - PAD, ox = x0 + 3 - PAD;
  const int TH2 = TH * TH;
  const int t0 = tid, t1 = tid + 256;
  const int ly0 = t0 / TH, lx0 = t0 - ly0 * TH;
  const int ly1 = t1 / TH, lx1 = t1 - ly1 * TH;
  const bool vv0 = t0 < TH2, vv1 = t1 < TH2;
  const size_t g0 = (size_t)(oy + ly0) * WP + ox + lx0;
  const size_t g1 = (size_t)(oy + ly1) * WP + ox + lx1;
  const int l0 = ly0 * SR + lx0, l1 = ly1 * SR + lx1;

  unsigned ra = 0, rb = 0;
  if (vv0) ra = attp[g0];
  if (vv1) rb = attp[g1];
  {
    if (vv0) { v2f v = unpack2(ra); atf[l0] = v.x; atf[TH * SR + l0] = v.y; }
    if (vv1) { v2f v = unpack2(rb); atf[l1] = v.x; atf[TH * SR + l1] = v.y; }
  }
  __syncthreads();

  const int px = tid & 15, py = tid >> 4;
  v2f acc2[8];
#pragma unroll
  for (int c = 0; c < 8; ++c) acc2[c] = (v2f){0.f, 0.f};

  for (int k = 0; k < nmp; ++k) {
    // issue next phase's global loads early (latency hidden by compute)
    if (k + 1 < nmp) {
      if (vv0) ra = attp[(size_t)(k + 1) * PL + g0];
      if (vv1) rb = attp[(size_t)(k + 1) * PL + g1];
    }
    // compute this phase: 2 fp32 planes, m = mbase+2k, mbase+2k+1
    const float* B0 = atf + (k & 1) * BUF;
    const float* B1 = B0 + TH * SR;
    const int m = mbase + 2 * k;
    const float* wb0 = memR + (size_t)(m * P * P) * C_CH;
    const float* wb1 = memR + (size_t)((m + 1) * P * P) * C_CH;
#pragma unroll
    for (int u = 0; u < P; ++u) {
      const float* ar0 = B0 + (py + u) * SR + px;
      const float* ar1 = B1 + (py + u) * SR + px;
#pragma unroll
      for (int v2_ = 0; v2_ < P; ++v2_) {
        float va = ar0[v2_];
        float vb = ar1[v2_];
        const v2f* w0 = (const v2f*)(wb0 + (u * P + v2_) * C_CH);
        const v2f* w1 = (const v2f*)(wb1 + (u * P + v2_) * C_CH);
        v2f a0 = {va, va}, b1v = {vb, vb};
#pragma unroll
        for (int c = 0; c < 8; ++c) {
          acc2[c] = __builtin_elementwise_fma(a0, w0[c], acc2[c]);
          acc2[c] = __builtin_elementwise_fma(b1v, w1[c], acc2[c]);
        }
      }
    }
    // write next phase's data into the other buffer (safe: last read of that
    // buffer finished before the barrier at the end of phase k-1)
    if (k + 1 < nmp) {
      float* W = atf + ((k + 1) & 1) * BUF;
      if (vv0) { v2f v = unpack2(ra); W[l0] = v.x; W[TH * SR + l0] = v.y; }
      if (vv1) { v2f v = unpack2(rb); W[l1] = v.x; W[TH * SR + l1] = v.y; }
      __syncthreads();
    }
  }

  const int gy = y0 + py, gx = x0 + px;
  int cy = min(P - 1, gy + PAD) - max(0, gy + PAD - (Hdim - 1)) + 1;
  int cx = min(P - 1, gx + PAD) - max(0, gx + PAD - (Wdim - 1)) + 1;
  float inv = 1.f / ((float)(cy * cx) + 1e-8f);
  if (isbg) {
    unsigned* outp = pbg2 + (size_t)((chunk * 2 + b) * 8) * HWdim + gy * Wdim + gx;
#pragma unroll
    for (int c = 0; c < 8; ++c)
      outp[(size_t)c * HWdim] = pack2(acc2[c].x * inv, acc2[c].y * inv);
  } else {
    float* outp = ftg + (size_t)b * CHW + gy * Wdim + gx;
#pragma unroll
    for (int c = 0; c < 8; ++c) {
      outp[(size_t)(2 * c) * HWdim]     = acc2[c].x * inv;
      outp[(size_t)(2 * c + 1) * HWdim] = acc2[c].y * inv;
    }
  }
}

// ---------------------------------------------------------------------------
// Sum f16 partial slabs -> final fbg (f32); fused pooled-mean (bg + tg).
// ---------------------------------------------------------------------------
__global__ __launch_bounds__(256) void k_sum(const unsigned* __restrict__ pbg2,
                                             const float* __restrict__ ftg,
                                             float* __restrict__ fbg,
                                             float* __restrict__ pooled)
{
  __shared__ float red[2][256];
  int bid = blockIdx.x;
  if (bid < 192) {
    int s = bid / 64;
    int rr = bid - s * 64;
    int b = rr >> 5;
    int cp = (rr >> 2) & 7;
    int q = rr & 3;
    size_t base = ((((size_t)(s * 16) * 2 + b) * 8) + cp) * HWdim + q * 4096;
    float* f0 = fbg + (size_t)(s * 2 + b) * CHW + (size_t)(2 * cp) * HWdim + q * 4096;
    float* f1 = f0 + HWdim;
    v2f ls = {0.f, 0.f};
    for (int t = threadIdx.x; t < 4096; t += 256) {
      v2f v = {0.f, 0.f};
#pragma unroll
      for (int ch = 0; ch < 16; ++ch)
        v += unpack2(pbg2[base + (size_t)ch * 16 * HWdim + t]);
      f0[t] = v.x;
      f1[t] = v.y;
      ls += v;
    }
    red[0][threadIdx.x] = ls.x;
    red[1][threadIdx.x] = ls.y;
    __syncthreads();
    for (int off = 128; off > 0; off >>= 1) {
      if ((int)threadIdx.x < off) {
        red[0][threadIdx.x] += red[0][threadIdx.x + off];
        red[1][threadIdx.x] += red[1][threadIdx.x + off];
      }
      __syncthreads();
    }
    if (threadIdx.x == 0) {
      gadd(&pooled[b * 16 + 2 * cp],     red[0][0] * (1.0f / (float)HWdim));
      gadd(&pooled[b * 16 + 2 * cp + 1], red[1][0] * (1.0f / (float)HWdim));
    }
  } else {
    int r = bid - 192;
    int s = r >> 7;
    int rr = r & 127;
    int b = rr >> 6;
    int c = (rr >> 2) & 15;
    int q = rr & 3;
    const float* f0 = ftg + (size_t)(s * 2 + b) * CHW + (size_t)c * HWdim + q * 4096;
    float ls = 0.f;
    for (int t = threadIdx.x; t < 4096; t += 256) ls += f0[t];
    red[0][threadIdx.x] = ls;
    __syncthreads();
    for (int off = 128; off > 0; off >>= 1) {
      if ((int)threadIdx.x < off) red[0][threadIdx.x] += red[0][threadIdx.x + off];
      __syncthreads();
    }
    if (threadIdx.x == 0)
      gadd(&pooled[32 + b * 16 + c], red[0][0] * (1.0f / (float)HWdim));
  }
}

// ---------------------------------------------------------------------------
// Fusion MLP + softmax weights
// ---------------------------------------------------------------------------
__global__ __launch_bounds__(128) void k_mlp(
    const float* __restrict__ pooled,
    const float* __restrict__ w1b, const float* __restrict__ b1b,
    const float* __restrict__ w2b, const float* __restrict__ b2b,
    const float* __restrict__ w1t, const float* __restrict__ b1t,
    const float* __restrict__ w2t, const float* __restrict__ b2t,
    float* __restrict__ wt)
{
  __shared__ float hdn[Bdim][4];
  __shared__ float lg[Bdim][48];
  int t = threadIdx.x;
  for (int br = 0; br < 2; ++br) {
    const float* w1 = br ? w1t : w1b;
    const float* b1 = br ? b1t : b1b;
    const float* w2 = br ? w2t : w2b;
    const float* b2 = br ? b2t : b2b;
    if (t < 8) {
      int b = t >> 2, h = t & 3;
      float s = b1[h];
      for (int c = 0; c < C_CH; ++c) s += pooled[br * 32 + b * 16 + c] * w1[h * 16 + c];
      hdn[b][h] = fmaxf(s, 0.f);
    }
    __syncthreads();
    if (t < 96) {
      int b = t / 48, j = t - b * 48;
      float s = b2[j];
      for (int h = 0; h < 4; ++h) s += hdn[b][h] * w2[j * 4 + h];
      lg[b][j] = s;
    }
    __syncthreads();
    if (t < 32) {
      int b = t >> 4, c = t & 15;
      float l0 = lg[b][c], l1 = lg[b][16 + c], l2 = lg[b][32 + c];
      float m = fmaxf(l0, fmaxf(l1, l2));
      float e0 = __expf(l0 - m), e1 = __expf(l1 - m), e2 = __expf(l2 - m);
      float inv = 1.f / (e0 + e1 + e2);
      wt[((br * 2 + b) * 3 + 0) * 16 + c] = e0 * inv;
      wt[((br * 2 + b) * 3 + 1) * 16 + c] = e1 * inv;
      wt[((br * 2 + b) * 3 + 2) * 16 + c] = e2 * inv;
    }
    __syncthreads();
  }
}

__global__ __launch_bounds__(256) void k_out(const float* __restrict__ fbg,
                                             const float* __restrict__ ftg,
                                             const float* __restrict__ wt,
                                             float* __restrict__ out)
{
  int idx = blockIdx.x * 256 + threadIdx.x;      // 0 .. 2*PAIR_ELEMS-1
  int br  = idx >> 19;                           // PAIR_ELEMS == 2^19
  int rem = idx & ((1 << 19) - 1);               // [b][c][HW]
  int b   = rem >> 18;                           // CHW == 2^18
  int off = rem & ((1 << 18) - 1);               // [c][HW]
  int c   = off >> 14;
  const float* f = (br == 0) ? fbg : ftg;
  int wbase = (br * 2 + b) * 3;
  float acc = 0.f;
#pragma unroll
  for (int s = 0; s < 3; ++s) {
    float v = f[(size_t)(s * 2 + b) * CHW + off];
    acc = fmaf(wt[(wbase + s) * 16 + c], v, acc);
  }
  out[idx] = acc;
}

// ---------------------------------------------------------------------------
extern "C" void kernel_launch(void* const* d_in, const int* in_sizes, int n_in,
                              void* d_out, int out_size, void* d_ws, size_t ws_size,
                              hipStream_t stream)
{
  const float* bg = (const float*)d_in[0];
  const float* tg = (const float*)d_in[1];
  const float* bg_mem[3]  = {(const float*)d_in[2],  (const float*)d_in[6],  (const float*)d_in[10]};
  const float* tg_mem[3]  = {(const float*)d_in[3],  (const float*)d_in[7],  (const float*)d_in[11]};
  const float* bg_temp[3] = {(const float*)d_in[4],  (const float*)d_in[8],  (const float*)d_in[12]};
  const float* tg_temp[3] = {(const float*)d_in[5],  (const float*)d_in[9],  (const float*)d_in[13]};
  const float* bg_fc1_w = (const float*)d_in[14];
  const float* bg_fc1_b = (const float*)d_in[15];
  const float* bg_fc2_w = (const float*)d_in[16];
  const float* bg_fc2_b = (const float*)d_in[17];
  const float* tg_fc1_w = (const float*)d_in[18];
  const float* tg_fc1_b = (const float*)d_in[19];
  const float* tg_fc2_w = (const float*)d_in[20];
  const float* tg_fc2_b = (const float*)d_in[21];

  float* ws = (float*)d_ws;
  unsigned* xpad2  = (unsigned*)ws;                        // 32 * PL
  unsigned* att2   = xpad2 + (size_t)32 * PL;              // 72 * PL
  float*    pooled = (float*)(att2 + (size_t)72 * PL);     // 64
  float*    wt     = pooled + 64;                          // 192
  float*    memT   = wt + 192;                             // 95,616
  float*    memR   = memT + 95616;                         // 95,616
  unsigned* pbg2   = (unsigned*)(memR + 95616);            // 3*16*2*8*HW u32
  float*    ftg    = (float*)(pbg2 + (size_t)3 * 16 * 2 * 8 * HWdim);  // 6*CHW
  float*    fbg    = ftg + (size_t)6 * CHW;                // 6*CHW

  unsigned* attbg2 = att2;                                 // [2][32] pair-planes
  unsigned* atttg2 = att2 + (size_t)64 * PL;               // [2][4]  pair-planes

  // zero xpad2 + att2 (borders) + pooled in one shot
  hipMemsetAsync(xpad2, 0, ((size_t)104 * PL) * 4 + 64 * 4, stream);

  const int   Ms[6] = {64, 64, 64, 8, 8, 8};
  const int   Ps[6] = {3, 5, 7, 3, 5, 7};
  const float* mems[6]  = {bg_mem[0], bg_mem[1], bg_mem[2], tg_mem[0], tg_mem[1], tg_mem[2]};
  const float* temps[6] = {bg_temp[0], bg_temp[1], bg_temp[2], tg_temp[0], tg_temp[1], tg_temp[2]};
  float* memTs[6]; float* memRs[6];
  PrepArgs pa;
  size_t off = 0;
  for (int k = 0; k < 6; ++k) {
    int D = C_CH * Ps[k] * Ps[k];
    memTs[k] = memT + off;
    memRs[k] = memR + off;
    pa.d[k] = {mems[k], temps[k], memTs[k], memRs[k], Ms[k], D, Ps[k]};
    off += (size_t)Ms[k] * D;
  }
  k_prep<<<dim3(196, 6), 256, 0, stream>>>(pa);
  k_padx<<<2048, 256, 0, stream>>>(bg, tg, xpad2);

  dim3 gs(16, 16, 4), bs(512);
  dim3 gr(8, 8, 34), brd(256);

  k_sim<3><<<gs, bs, 0, stream>>>(xpad2, memTs[0], memTs[3], attbg2, atttg2);
  k_read<3><<<gr, brd, 0, stream>>>(attbg2, atttg2, memRs[0], memRs[3],
                                    pbg2 + (size_t)0 * 16 * 2 * 8 * HWdim,
                                    ftg + (size_t)0 * 2 * CHW);
  k_sim<5><<<gs, bs, 0, stream>>>(xpad2, memTs[1], memTs[4], attbg2, atttg2);
  k_read<5><<<gr, brd, 0, stream>>>(attbg2, atttg2, memRs[1], memRs[4],
                                    pbg2 + (size_t)1 * 16 * 2 * 8 * HWdim,
                                    ftg + (size_t)1 * 2 * CHW);
  k_sim<7><<<gs, bs, 0, stream>>>(xpad2, memTs[2], memTs[5], attbg2, atttg2);
  k_read<7><<<gr, brd, 0, stream>>>(attbg2, atttg2, memRs[2], memRs[5],
                                    pbg2 + (size_t)2 * 16 * 2 * 8 * HWdim,
                                    ftg + (size_t)2 * 2 * CHW);

  k_sum<<<576, 256, 0, stream>>>(pbg2, ftg, fbg, pooled);
  k_mlp<<<1, 128, 0, stream>>>(pooled, bg_fc1_w, bg_fc1_b, bg_fc2_w, bg_fc2_b,
                               tg_fc1_w, tg_fc1_b, tg_fc2_w, tg_fc2_b, wt);
  k_out<<<(2 * PAIR_ELEMS) / 256, 256, 0, stream>>>(fbg, ftg, wt, (float*)d_out);
}

// Round 16
// 542.600 us; speedup vs baseline: 1.1624x; 1.1624x over previous
//
#include <hip/hip_runtime.h>

#define C_CH 16
#define Hdim 128
#define Wdim 128
#define HWdim 16384
#define CHW (C_CH * HWdim)                 // 262144 floats: one [C][H][W] slab
#define Bdim 2
#define PAIR_ELEMS (Bdim * CHW)            // 524288

// padded canvas geometry (border 3 = max P/2, zeroed once per launch)
#define HP 134
#define WP 136
#define PL (HP * WP)                       // 18224 elements per plane

typedef float v2f __attribute__((ext_vector_type(2)));
typedef _Float16 h2 __attribute__((ext_vector_type(2)));

__device__ __forceinline__ v2f unpack2(unsigned u) {
  h2 h = __builtin_bit_cast(h2, u);
  return (v2f){(float)h.x, (float)h.y};
}
__device__ __forceinline__ unsigned pack2(float a, float b) {
  h2 h = {(_Float16)a, (_Float16)b};
  return __builtin_bit_cast(unsigned, h);
}

__device__ __forceinline__ void gadd(float* p, float v) {
  __hip_atomic_fetch_add(p, v, __ATOMIC_RELAXED, __HIP_MEMORY_SCOPE_AGENT);
}

// conflict-free LDS row strides (elements):
//  8x8 reads:  SR % 8 == 4;  16x4 reads: SR % 32 in {8,16,24}
template<int P> struct SimSR { static constexpr int v = (P == 7) ? 20 : 12; };

// ---------------------------------------------------------------------------
// Prep: memT[d][m] = mem * temp/sqrt(D)   (f32, m-contiguous)
//       memR[m][u][v][c]                  (f32, kernel-flipped, c-contiguous)
// ---------------------------------------------------------------------------
struct PrepDesc {
  const float* mem;
  const float* temp;
  float* memT;
  float* memR;
  int M, D, P;
};
struct PrepArgs { PrepDesc d[6]; };

__global__ __launch_bounds__(256) void k_prep(PrepArgs a) {
  PrepDesc de = a.d[blockIdx.y];
  int n = de.M * de.D;
  int idx = blockIdx.x * 256 + threadIdx.x;
  if (idx >= n) return;
  int m = idx / de.D;
  int d = idx - m * de.D;
  float v = de.mem[idx];
  float sc = de.temp[0] / sqrtf((float)de.D);
  de.memT[d * de.M + m] = v * sc;
  int pp = de.P * de.P;
  int c = d / pp;
  int r = d - c * pp;
  int i = r / de.P;
  int j = r - i * de.P;
  de.memR[((m * de.P + (de.P - 1 - i)) * de.P + (de.P - 1 - j)) * C_CH + c] = v;
}

// ---------------------------------------------------------------------------
// Build f16 c-pair-packed padded canvas.
// ---------------------------------------------------------------------------
__global__ __launch_bounds__(256) void k_padx(const float* __restrict__ bg,
                                              const float* __restrict__ tg,
                                              unsigned* __restrict__ xpad2)
{
  int idx = blockIdx.x * 256 + threadIdx.x;     // 32 pair-planes * HW
  int pp = idx >> 14;
  int hw = idx & (HWdim - 1);
  int y = hw >> 7, x = hw & 127;
  int z = pp >> 3, cp = pp & 7;
  const float* src = (z < 2) ? bg : tg;
  int b = z & 1;
  float a = src[((b * C_CH + 2 * cp) << 14) + hw];
  float bb = src[((b * C_CH + 2 * cp + 1) << 14) + hw];
  xpad2[(size_t)pp * PL + (y + 3) * WP + (x + 3)] = pack2(a, bb);
}

// ---------------------------------------------------------------------------
// Sim conv + softmax -> att2 (m-pair-packed f16 padded planes).  [R11 form]
// 8x8 tile, 512 thr = 8 waves; one dispatch per scale (template P).
// ---------------------------------------------------------------------------
template<int P>
__device__ __forceinline__ void sim_core_bg(
    const unsigned* __restrict__ xt2, float* __restrict__ red,
    const float* __restrict__ memT, unsigned* __restrict__ att2,
    int wv, int lane, int x0, int y0)
{
  constexpr int TH = 8 + P - 1, SR = SimSR<P>::v;
  constexpr int M = 64;
  const int px = lane & 7, py = lane >> 3;
  const int m0 = wv * 8;
  v2f acc2[4];
#pragma unroll
  for (int mm = 0; mm < 4; ++mm) acc2[mm] = (v2f){0.f, 0.f};

  for (int cp = 0; cp < 8; ++cp) {
#pragma unroll
    for (int i = 0; i < P; ++i) {
#pragma unroll
      for (int j = 0; j < P; ++j) {
        v2f vp = unpack2(xt2[(cp * TH + py + i) * SR + (px + j)]);
        const v2f* w0 = (const v2f*)(memT + (size_t)((((2 * cp) * P + i) * P + j)) * M + m0);
        const v2f* w1 = (const v2f*)(memT + (size_t)((((2 * cp + 1) * P + i) * P + j)) * M + m0);
        v2f v0 = {vp.x, vp.x}, v1 = {vp.y, vp.y};
#pragma unroll
        for (int mm = 0; mm < 4; ++mm) {
          acc2[mm] = __builtin_elementwise_fma(v0, w0[mm], acc2[mm]);
          acc2[mm] = __builtin_elementwise_fma(v1, w1[mm], acc2[mm]);
        }
      }
    }
  }

  float acc[8];
#pragma unroll
  for (int mm = 0; mm < 4; ++mm) { acc[2 * mm] = acc2[mm].x; acc[2 * mm + 1] = acc2[mm].y; }

  float pm = acc[0];
#pragma unroll
  for (int mm = 1; mm < 8; ++mm) pm = fmaxf(pm, acc[mm]);
  red[wv * 64 + lane] = pm;
  __syncthreads();
  float gm = red[lane];
#pragma unroll
  for (int w = 1; w < 8; ++w) gm = fmaxf(gm, red[w * 64 + lane]);
  __syncthreads();
  float ps = 0.f;
#pragma unroll
  for (int mm = 0; mm < 8; ++mm) { acc[mm] = __expf(acc[mm] - gm); ps += acc[mm]; }
  red[wv * 64 + lane] = ps;
  __syncthreads();
  float tot = 0.f;
#pragma unroll
  for (int w = 0; w < 8; ++w) tot += red[w * 64 + lane];
  float inv = 1.f / tot;

  const int gy = y0 + py, gx = x0 + px;
#pragma unroll
  for (int k = 0; k < 4; ++k) {
    int mp = (m0 >> 1) + k;
    att2[(size_t)mp * PL + (gy + 3) * WP + (gx + 3)] =
        pack2(acc[2 * k] * inv, acc[2 * k + 1] * inv);
  }
}

template<int P>
__device__ __forceinline__ void sim_core_tg(
    const unsigned* __restrict__ xt2, float* __restrict__ red,  // [8][8][64]
    const float* __restrict__ memT, unsigned* __restrict__ att2,
    int wv, int lane, int x0, int y0)
{
  constexpr int TH = 8 + P - 1, SR = SimSR<P>::v;
  constexpr int M = 8;
  const int px = lane & 7, py = lane >> 3;
  const int cp = wv;
  v2f acc2[4];
#pragma unroll
  for (int mm = 0; mm < 4; ++mm) acc2[mm] = (v2f){0.f, 0.f};

#pragma unroll
  for (int i = 0; i < P; ++i) {
#pragma unroll
    for (int j = 0; j < P; ++j) {
      v2f vp = unpack2(xt2[(cp * TH + py + i) * SR + (px + j)]);
      const v2f* w0 = (const v2f*)(memT + (size_t)((((2 * cp) * P + i) * P + j)) * M);
      const v2f* w1 = (const v2f*)(memT + (size_t)((((2 * cp + 1) * P + i) * P + j)) * M);
      v2f v0 = {vp.x, vp.x}, v1 = {vp.y, vp.y};
#pragma unroll
      for (int mm = 0; mm < 4; ++mm) {
        acc2[mm] = __builtin_elementwise_fma(v0, w0[mm], acc2[mm]);
        acc2[mm] = __builtin_elementwise_fma(v1, w1[mm], acc2[mm]);
      }
    }
  }

#pragma unroll
  for (int mm = 0; mm < 4; ++mm) {
    red[(wv * 8 + 2 * mm) * 64 + lane]     = acc2[mm].x;
    red[(wv * 8 + 2 * mm + 1) * 64 + lane] = acc2[mm].y;
  }
  __syncthreads();

  float lg[8];
#pragma unroll
  for (int m = 0; m < 8; ++m) {
    float s = red[m * 64 + lane];
#pragma unroll
    for (int w = 1; w < 8; ++w) s += red[(w * 8 + m) * 64 + lane];
    lg[m] = s;
  }
  float gm = lg[0];
#pragma unroll
  for (int m = 1; m < 8; ++m) gm = fmaxf(gm, lg[m]);
  float tot = 0.f;
#pragma unroll
  for (int m = 0; m < 8; ++m) { lg[m] = __expf(lg[m] - gm); tot += lg[m]; }
  float inv = 1.f / tot;

  const int gy = y0 + py, gx = x0 + px;
  if (wv < 4)
    att2[(size_t)wv * PL + (gy + 3) * WP + (gx + 3)] =
        pack2(lg[2 * wv] * inv, lg[2 * wv + 1] * inv);
}

template<int P>
__global__ __launch_bounds__(512, 8) void k_sim(
    const unsigned* __restrict__ xpad2,
    const float* __restrict__ memTbg, const float* __restrict__ memTtg,
    unsigned* __restrict__ attbg2,   // [2][32] pair-planes
    unsigned* __restrict__ atttg2)   // [2][4]  pair-planes
{
  constexpr int PAD = P / 2, TH = 8 + P - 1, SR = SimSR<P>::v;
  __shared__ unsigned xt2[8 * TH * SR];
  __shared__ float red[8 * 8 * 64];

  const int tid = threadIdx.x;
  const int wv = __builtin_amdgcn_readfirstlane(tid >> 6);
  const int lane = tid & 63;
  const int x0 = blockIdx.x * 8, y0 = blockIdx.y * 8;
  const int z = blockIdx.z;
  const bool isbg = z < 2;
  const int b = z & 1;

  const unsigned* xp = xpad2 + (size_t)(z * 8) * PL;
  const int oy = y0 + 3 - PAD, ox = x0 + 3 - PAD;
  for (int t = tid; t < 8 * TH * TH; t += 512) {
    int cp = t / (TH * TH);
    int r = t - cp * (TH * TH);
    int ly = r / TH, lx = r - ly * TH;
    xt2[(cp * TH + ly) * SR + lx] = xp[(size_t)cp * PL + (oy + ly) * WP + ox + lx];
  }
  __syncthreads();

  if (isbg) sim_core_bg<P>(xt2, red, memTbg, attbg2 + (size_t)(b * 32) * PL, wv, lane, x0, y0);
  else      sim_core_tg<P>(xt2, red, memTtg, atttg2 + (size_t)(b * 4) * PL, wv, lane, x0, y0);
}

// ---------------------------------------------------------------------------
// Read conv (pipelined hybrid, 128-VGPR budget): 16x16 tile, 1 thread = 1
// pixel, fp32 inner loop; f16 traffic. Double-buffered staging per m-pair
// phase: issue phase k+1 global loads into regs, compute phase k from LDS
// buf k&1, write regs to buf (k+1)&1. launch_bounds(256,4) -> <=128 VGPR,
// no scratch spill (R15's (256,8)/64-VGPR cap spilled: FETCH/WRITE x17).
// bg: 2 phases (chunk of 4 m); tg: 4 phases (8 m) -> fp32 final.
// z: 0,1 tg b; 2..33 bg chunk=(z-2)>>1, b=(z-2)&1.  SR=24 conflict-free.
// ---------------------------------------------------------------------------
template<int P>
__global__ __launch_bounds__(256, 4) void k_read(
    const unsigned* __restrict__ attbg2,   // [2][32] pair-planes
    const unsigned* __restrict__ atttg2,   // [2][4]  pair-planes
    const float* __restrict__ memRbg, const float* __restrict__ memRtg,
    unsigned* __restrict__ pbg2,           // [16][2][8][HW] u32 (this scale)
    float* __restrict__ ftg)               // [2 b][CHW]       (this scale)
{
  constexpr int PAD = P / 2, TH = 16 + P - 1, SR = 24;
  constexpr int BUF = 2 * TH * SR;         // one buffer: 2 fp32 planes
  __shared__ float atf[2 * BUF];

  const int tid = threadIdx.x;
  const int x0 = blockIdx.x * 16, y0 = blockIdx.y * 16;
  const int z = blockIdx.z;
  const bool isbg = z >= 2;
  const int b = isbg ? ((z - 2) & 1) : z;
  const int chunk = isbg ? ((z - 2) >> 1) : 0;
  const int nmp = isbg ? 2 : 4;            // m-pair phases
  const int mbase = isbg ? chunk * 4 : 0;
  const unsigned* attp = isbg ? (attbg2 + (size_t)(b * 32 + chunk * 2) * PL)
                              : (atttg2 + (size_t)(b * 4) * PL);
  const float* memR = isbg ? memRbg : memRtg;

  // staging geometry: TH*TH <= 484 < 512 -> 2 slots/thread
  const int oy = y0 + 3 - PAD, ox = x0 + 3 - PAD;
  const int TH2 = TH * TH;
  const int t0 = tid, t1 = tid + 256;
  const int ly0 = t0 / TH, lx0 = t0 - ly0 * TH;
  const int ly1 = t1 / TH, lx1 = t1 - ly1 * TH;
  const bool vv0 = t0 < TH2, vv1 = t1 < TH2;
  const size_t g0 = (size_t)(oy + ly0) * WP + ox + lx0;
  const size_t g1 = (size_t)(oy + ly1) * WP + ox + lx1;
  const int l0 = ly0 * SR + lx0, l1 = ly1 * SR + lx1;

  unsigned ra = 0, rb = 0;
  if (vv0) ra = attp[g0];
  if (vv1) rb = attp[g1];
  {
    if (vv0) { v2f v = unpack2(ra); atf[l0] = v.x; atf[TH * SR + l0] = v.y; }
    if (vv1) { v2f v = unpack2(rb); atf[l1] = v.x; atf[TH * SR + l1] = v.y; }
  }
  __syncthreads();

  const int px = tid & 15, py = tid >> 4;
  v2f acc2[8];
#pragma unroll
  for (int c = 0; c < 8; ++c) acc2[c] = (v2f){0.f, 0.f};

  for (int k = 0; k < nmp; ++k) {
    // issue next phase's global loads early (latency hidden by compute)
    if (k + 1 < nmp) {
      if (vv0) ra = attp[(size_t)(k + 1) * PL + g0];
      if (vv1) rb = attp[(size_t)(k + 1) * PL + g1];
    }
    // compute this phase: 2 fp32 planes, m = mbase+2k, mbase+2k+1
    const float* B0 = atf + (k & 1) * BUF;
    const float* B1 = B0 + TH * SR;
    const int m = mbase + 2 * k;
    const float* wb0 = memR + (size_t)(m * P * P) * C_CH;
    const float* wb1 = memR + (size_t)((m + 1) * P * P) * C_CH;
#pragma unroll
    for (int u = 0; u < P; ++u) {
      const float* ar0 = B0 + (py + u) * SR + px;
      const float* ar1 = B1 + (py + u) * SR + px;
#pragma unroll
      for (int v2_ = 0; v2_ < P; ++v2_) {
        float va = ar0[v2_];
        float vb = ar1[v2_];
        const v2f* w0 = (const v2f*)(wb0 + (u * P + v2_) * C_CH);
        const v2f* w1 = (const v2f*)(wb1 + (u * P + v2_) * C_CH);
        v2f a0 = {va, va}, b1v = {vb, vb};
#pragma unroll
        for (int c = 0; c < 8; ++c) {
          acc2[c] = __builtin_elementwise_fma(a0, w0[c], acc2[c]);
          acc2[c] = __builtin_elementwise_fma(b1v, w1[c], acc2[c]);
        }
      }
    }
    // write next phase's data into the other buffer
    if (k + 1 < nmp) {
      float* W = atf + ((k + 1) & 1) * BUF;
      if (vv0) { v2f v = unpack2(ra); W[l0] = v.x; W[TH * SR + l0] = v.y; }
      if (vv1) { v2f v = unpack2(rb); W[l1] = v.x; W[TH * SR + l1] = v.y; }
      __syncthreads();
    }
  }

  const int gy = y0 + py, gx = x0 + px;
  int cy = min(P - 1, gy + PAD) - max(0, gy + PAD - (Hdim - 1)) + 1;
  int cx = min(P - 1, gx + PAD) - max(0, gx + PAD - (Wdim - 1)) + 1;
  float inv = 1.f / ((float)(cy * cx) + 1e-8f);
  if (isbg) {
    unsigned* outp = pbg2 + (size_t)((chunk * 2 + b) * 8) * HWdim + gy * Wdim + gx;
#pragma unroll
    for (int c = 0; c < 8; ++c)
      outp[(size_t)c * HWdim] = pack2(acc2[c].x * inv, acc2[c].y * inv);
  } else {
    float* outp = ftg + (size_t)b * CHW + gy * Wdim + gx;
#pragma unroll
    for (int c = 0; c < 8; ++c) {
      outp[(size_t)(2 * c) * HWdim]     = acc2[c].x * inv;
      outp[(size_t)(2 * c + 1) * HWdim] = acc2[c].y * inv;
    }
  }
}

// ---------------------------------------------------------------------------
// Sum f16 partial slabs -> final fbg (f32); fused pooled-mean (bg + tg).
// ---------------------------------------------------------------------------
__global__ __launch_bounds__(256) void k_sum(const unsigned* __restrict__ pbg2,
                                             const float* __restrict__ ftg,
                                             float* __restrict__ fbg,
                                             float* __restrict__ pooled)
{
  __shared__ float red[2][256];
  int bid = blockIdx.x;
  if (bid < 192) {
    int s = bid / 64;
    int rr = bid - s * 64;
    int b = rr >> 5;
    int cp = (rr >> 2) & 7;
    int q = rr & 3;
    size_t base = ((((size_t)(s * 16) * 2 + b) * 8) + cp) * HWdim + q * 4096;
    float* f0 = fbg + (size_t)(s * 2 + b) * CHW + (size_t)(2 * cp) * HWdim + q * 4096;
    float* f1 = f0 + HWdim;
    v2f ls = {0.f, 0.f};
    for (int t = threadIdx.x; t < 4096; t += 256) {
      v2f v = {0.f, 0.f};
#pragma unroll
      for (int ch = 0; ch < 16; ++ch)
        v += unpack2(pbg2[base + (size_t)ch * 16 * HWdim + t]);
      f0[t] = v.x;
      f1[t] = v.y;
      ls += v;
    }
    red[0][threadIdx.x] = ls.x;
    red[1][threadIdx.x] = ls.y;
    __syncthreads();
    for (int off = 128; off > 0; off >>= 1) {
      if ((int)threadIdx.x < off) {
        red[0][threadIdx.x] += red[0][threadIdx.x + off];
        red[1][threadIdx.x] += red[1][threadIdx.x + off];
      }
      __syncthreads();
    }
    if (threadIdx.x == 0) {
      gadd(&pooled[b * 16 + 2 * cp],     red[0][0] * (1.0f / (float)HWdim));
      gadd(&pooled[b * 16 + 2 * cp + 1], red[1][0] * (1.0f / (float)HWdim));
    }
  } else {
    int r = bid - 192;
    int s = r >> 7;
    int rr = r & 127;
    int b = rr >> 6;
    int c = (rr >> 2) & 15;
    int q = rr & 3;
    const float* f0 = ftg + (size_t)(s * 2 + b) * CHW + (size_t)c * HWdim + q * 4096;
    float ls = 0.f;
    for (int t = threadIdx.x; t < 4096; t += 256) ls += f0[t];
    red[0][threadIdx.x] = ls;
    __syncthreads();
    for (int off = 128; off > 0; off >>= 1) {
      if ((int)threadIdx.x < off) red[0][threadIdx.x] += red[0][threadIdx.x + off];
      __syncthreads();
    }
    if (threadIdx.x == 0)
      gadd(&pooled[32 + b * 16 + c], red[0][0] * (1.0f / (float)HWdim));
  }
}

// ---------------------------------------------------------------------------
// Fusion MLP + softmax weights
// ---------------------------------------------------------------------------
__global__ __launch_bounds__(128) void k_mlp(
    const float* __restrict__ pooled,
    const float* __restrict__ w1b, const float* __restrict__ b1b,
    const float* __restrict__ w2b, const float* __restrict__ b2b,
    const float* __restrict__ w1t, const float* __restrict__ b1t,
    const float* __restrict__ w2t, const float* __restrict__ b2t,
    float* __restrict__ wt)
{
  __shared__ float hdn[Bdim][4];
  __shared__ float lg[Bdim][48];
  int t = threadIdx.x;
  for (int br = 0; br < 2; ++br) {
    const float* w1 = br ? w1t : w1b;
    const float* b1 = br ? b1t : b1b;
    const float* w2 = br ? w2t : w2b;
    const float* b2 = br ? b2t : b2b;
    if (t < 8) {
      int b = t >> 2, h = t & 3;
      float s = b1[h];
      for (int c = 0; c < C_CH; ++c) s += pooled[br * 32 + b * 16 + c] * w1[h * 16 + c];
      hdn[b][h] = fmaxf(s, 0.f);
    }
    __syncthreads();
    if (t < 96) {
      int b = t / 48, j = t - b * 48;
      float s = b2[j];
      for (int h = 0; h < 4; ++h) s += hdn[b][h] * w2[j * 4 + h];
      lg[b][j] = s;
    }
    __syncthreads();
    if (t < 32) {
      int b = t >> 4, c = t & 15;
      float l0 = lg[b][c], l1 = lg[b][16 + c], l2 = lg[b][32 + c];
      float m = fmaxf(l0, fmaxf(l1, l2));
      float e0 = __expf(l0 - m), e1 = __expf(l1 - m), e2 = __expf(l2 - m);
      float inv = 1.f / (e0 + e1 + e2);
      wt[((br * 2 + b) * 3 + 0) * 16 + c] = e0 * inv;
      wt[((br * 2 + b) * 3 + 1) * 16 + c] = e1 * inv;
      wt[((br * 2 + b) * 3 + 2) * 16 + c] = e2 * inv;
    }
    __syncthreads();
  }
}

__global__ __launch_bounds__(256) void k_out(const float* __restrict__ fbg,
                                             const float* __restrict__ ftg,
                                             const float* __restrict__ wt,
                                             float* __restrict__ out)
{
  int idx = blockIdx.x * 256 + threadIdx.x;      // 0 .. 2*PAIR_ELEMS-1
  int br  = idx >> 19;                           // PAIR_ELEMS == 2^19
  int rem = idx & ((1 << 19) - 1);               // [b][c][HW]
  int b   = rem >> 18;                           // CHW == 2^18
  int off = rem & ((1 << 18) - 1);               // [c][HW]
  int c   = off >> 14;
  const float* f = (br == 0) ? fbg : ftg;
  int wbase = (br * 2 + b) * 3;
  float acc = 0.f;
#pragma unroll
  for (int s = 0; s < 3; ++s) {
    float v = f[(size_t)(s * 2 + b) * CHW + off];
    acc = fmaf(wt[(wbase + s) * 16 + c], v, acc);
  }
  out[idx] = acc;
}

// ---------------------------------------------------------------------------
extern "C" void kernel_launch(void* const* d_in, const int* in_sizes, int n_in,
                              void* d_out, int out_size, void* d_ws, size_t ws_size,
                              hipStream_t stream)
{
  const float* bg = (const float*)d_in[0];
  const float* tg = (const float*)d_in[1];
  const float* bg_mem[3]  = {(const float*)d_in[2],  (const float*)d_in[6],  (const float*)d_in[10]};
  const float* tg_mem[3]  = {(const float*)d_in[3],  (const float*)d_in[7],  (const float*)d_in[11]};
  const float* bg_temp[3] = {(const float*)d_in[4],  (const float*)d_in[8],  (const float*)d_in[12]};
  const float* tg_temp[3] = {(const float*)d_in[5],  (const float*)d_in[9],  (const float*)d_in[13]};
  const float* bg_fc1_w = (const float*)d_in[14];
  const float* bg_fc1_b = (const float*)d_in[15];
  const float* bg_fc2_w = (const float*)d_in[16];
  const float* bg_fc2_b = (const float*)d_in[17];
  const float* tg_fc1_w = (const float*)d_in[18];
  const float* tg_fc1_b = (const float*)d_in[19];
  const float* tg_fc2_w = (const float*)d_in[20];
  const float* tg_fc2_b = (const float*)d_in[21];

  float* ws = (float*)d_ws;
  unsigned* xpad2  = (unsigned*)ws;                        // 32 * PL
  unsigned* att2   = xpad2 + (size_t)32 * PL;              // 72 * PL
  float*    pooled = (float*)(att2 + (size_t)72 * PL);     // 64
  float*    wt     = pooled + 64;                          // 192
  float*    memT   = wt + 192;                             // 95,616
  float*    memR   = memT + 95616;                         // 95,616
  unsigned* pbg2   = (unsigned*)(memR + 95616);            // 3*16*2*8*HW u32
  float*    ftg    = (float*)(pbg2 + (size_t)3 * 16 * 2 * 8 * HWdim);  // 6*CHW
  float*    fbg    = ftg + (size_t)6 * CHW;                // 6*CHW

  unsigned* attbg2 = att2;                                 // [2][32] pair-planes
  unsigned* atttg2 = att2 + (size_t)64 * PL;               // [2][4]  pair-planes

  // zero xpad2 + att2 (borders) + pooled in one shot
  hipMemsetAsync(xpad2, 0, ((size_t)104 * PL) * 4 + 64 * 4, stream);

  const int   Ms[6] = {64, 64, 64, 8, 8, 8};
  const int   Ps[6] = {3, 5, 7, 3, 5, 7};
  const float* mems[6]  = {bg_mem[0], bg_mem[1], bg_mem[2], tg_mem[0], tg_mem[1], tg_mem[2]};
  const float* temps[6] = {bg_temp[0], bg_temp[1], bg_temp[2], tg_temp[0], tg_temp[1], tg_temp[2]};
  float* memTs[6]; float* memRs[6];
  PrepArgs pa;
  size_t off = 0;
  for (int k = 0; k < 6; ++k) {
    int D = C_CH * Ps[k] * Ps[k];
    memTs[k] = memT + off;
    memRs[k] = memR + off;
    pa.d[k] = {mems[k], temps[k], memTs[k], memRs[k], Ms[k], D, Ps[k]};
    off += (size_t)Ms[k] * D;
  }
  k_prep<<<dim3(196, 6), 256, 0, stream>>>(pa);
  k_padx<<<2048, 256, 0, stream>>>(bg, tg, xpad2);

  dim3 gs(16, 16, 4), bs(512);
  dim3 gr(8, 8, 34), brd(256);

  k_sim<3><<<gs, bs, 0, stream>>>(xpad2, memTs[0], memTs[3], attbg2, atttg2);
  k_read<3><<<gr, brd, 0, stream>>>(attbg2, atttg2, memRs[0], memRs[3],
                                    pbg2 + (size_t)0 * 16 * 2 * 8 * HWdim,
                                    ftg + (size_t)0 * 2 * CHW);
  k_sim<5><<<gs, bs, 0, stream>>>(xpad2, memTs[1], memTs[4], attbg2, atttg2);
  k_read<5><<<gr, brd, 0, stream>>>(attbg2, atttg2, memRs[1], memRs[4],
                                    pbg2 + (size_t)1 * 16 * 2 * 8 * HWdim,
                                    ftg + (size_t)1 * 2 * CHW);
  k_sim<7><<<gs, bs, 0, stream>>>(xpad2, memTs[2], memTs[5], attbg2, atttg2);
  k_read<7><<<gr, brd, 0, stream>>>(attbg2, atttg2, memRs[2], memRs[5],
                                    pbg2 + (size_t)2 * 16 * 2 * 8 * HWdim,
                                    ftg + (size_t)2 * 2 * CHW);

  k_sum<<<576, 256, 0, stream>>>(pbg2, ftg, fbg, pooled);
  k_mlp<<<1, 128, 0, stream>>>(pooled, bg_fc1_w, bg_fc1_b, bg_fc2_w, bg_fc2_b,
                               tg_fc1_w, tg_fc1_b, tg_fc2_w, tg_fc2_b, wt);
  k_out<<<(2 * PAIR_ELEMS) / 256, 256, 0, stream>>>(fbg, ftg, wt, (float*)d_out);
}

// Round 17
// 313.837 us; speedup vs baseline: 2.0097x; 1.7289x over previous
//
#include <hip/hip_runtime.h>

#define C_CH 16
#define Hdim 128
#define Wdim 128
#define HWdim 16384
#define CHW (C_CH * HWdim)                 // 262144 floats: one [C][H][W] slab
#define Bdim 2
#define PAIR_ELEMS (Bdim * CHW)            // 524288

// padded canvas geometry (border 3 = max P/2, zeroed once per launch)
#define HP 134
#define WP 136
#define PL (HP * WP)                       // 18224 elements per plane

typedef float v2f __attribute__((ext_vector_type(2)));
typedef _Float16 h2 __attribute__((ext_vector_type(2)));

__device__ __forceinline__ v2f unpack2(unsigned u) {
  h2 h = __builtin_bit_cast(h2, u);
  return (v2f){(float)h.x, (float)h.y};
}
__device__ __forceinline__ unsigned pack2(float a, float b) {
  h2 h = {(_Float16)a, (_Float16)b};
  return __builtin_bit_cast(unsigned, h);
}

__device__ __forceinline__ void gadd(float* p, float v) {
  __hip_atomic_fetch_add(p, v, __ATOMIC_RELAXED, __HIP_MEMORY_SCOPE_AGENT);
}

// conflict-free LDS row strides (elements):
//  8x8 reads:  SR % 8 == 4;  16x4 reads: SR % 32 in {8,16,24}
template<int P> struct SimSR { static constexpr int v = (P == 7) ? 20 : 12; };

// ---------------------------------------------------------------------------
// Prep: memT[d][m] = mem * temp/sqrt(D)   (f32, m-contiguous)
//       memR[m][u][v][c]                  (f32, kernel-flipped, c-contiguous)
// ---------------------------------------------------------------------------
struct PrepDesc {
  const float* mem;
  const float* temp;
  float* memT;
  float* memR;
  int M, D, P;
};
struct PrepArgs { PrepDesc d[6]; };

__global__ __launch_bounds__(256) void k_prep(PrepArgs a) {
  PrepDesc de = a.d[blockIdx.y];
  int n = de.M * de.D;
  int idx = blockIdx.x * 256 + threadIdx.x;
  if (idx >= n) return;
  int m = idx / de.D;
  int d = idx - m * de.D;
  float v = de.mem[idx];
  float sc = de.temp[0] / sqrtf((float)de.D);
  de.memT[d * de.M + m] = v * sc;
  int pp = de.P * de.P;
  int c = d / pp;
  int r = d - c * pp;
  int i = r / de.P;
  int j = r - i * de.P;
  de.memR[((m * de.P + (de.P - 1 - i)) * de.P + (de.P - 1 - j)) * C_CH + c] = v;
}

// ---------------------------------------------------------------------------
// Build f16 c-pair-packed padded canvas.
// ---------------------------------------------------------------------------
__global__ __launch_bounds__(256) void k_padx(const float* __restrict__ bg,
                                              const float* __restrict__ tg,
                                              unsigned* __restrict__ xpad2)
{
  int idx = blockIdx.x * 256 + threadIdx.x;     // 32 pair-planes * HW
  int pp = idx >> 14;
  int hw = idx & (HWdim - 1);
  int y = hw >> 7, x = hw & 127;
  int z = pp >> 3, cp = pp & 7;
  const float* src = (z < 2) ? bg : tg;
  int b = z & 1;
  float a = src[((b * C_CH + 2 * cp) << 14) + hw];
  float bb = src[((b * C_CH + 2 * cp + 1) << 14) + hw];
  xpad2[(size_t)pp * PL + (y + 3) * WP + (x + 3)] = pack2(a, bb);
}

// ---------------------------------------------------------------------------
// Sim conv + softmax -> att2 (m-pair-packed f16 padded planes).  [R11 form]
// 8x8 tile, 512 thr = 8 waves; one dispatch per scale (template P).
// ---------------------------------------------------------------------------
template<int P>
__device__ __forceinline__ void sim_core_bg(
    const unsigned* __restrict__ xt2, float* __restrict__ red,
    const float* __restrict__ memT, unsigned* __restrict__ att2,
    int wv, int lane, int x0, int y0)
{
  constexpr int TH = 8 + P - 1, SR = SimSR<P>::v;
  constexpr int M = 64;
  const int px = lane & 7, py = lane >> 3;
  const int m0 = wv * 8;
  v2f acc2[4];
#pragma unroll
  for (int mm = 0; mm < 4; ++mm) acc2[mm] = (v2f){0.f, 0.f};

  for (int cp = 0; cp < 8; ++cp) {
#pragma unroll
    for (int i = 0; i < P; ++i) {
#pragma unroll
      for (int j = 0; j < P; ++j) {
        v2f vp = unpack2(xt2[(cp * TH + py + i) * SR + (px + j)]);
        const v2f* w0 = (const v2f*)(memT + (size_t)((((2 * cp) * P + i) * P + j)) * M + m0);
        const v2f* w1 = (const v2f*)(memT + (size_t)((((2 * cp + 1) * P + i) * P + j)) * M + m0);
        v2f v0 = {vp.x, vp.x}, v1 = {vp.y, vp.y};
#pragma unroll
        for (int mm = 0; mm < 4; ++mm) {
          acc2[mm] = __builtin_elementwise_fma(v0, w0[mm], acc2[mm]);
          acc2[mm] = __builtin_elementwise_fma(v1, w1[mm], acc2[mm]);
        }
      }
    }
  }

  float acc[8];
#pragma unroll
  for (int mm = 0; mm < 4; ++mm) { acc[2 * mm] = acc2[mm].x; acc[2 * mm + 1] = acc2[mm].y; }

  float pm = acc[0];
#pragma unroll
  for (int mm = 1; mm < 8; ++mm) pm = fmaxf(pm, acc[mm]);
  red[wv * 64 + lane] = pm;
  __syncthreads();
  float gm = red[lane];
#pragma unroll
  for (int w = 1; w < 8; ++w) gm = fmaxf(gm, red[w * 64 + lane]);
  __syncthreads();
  float ps = 0.f;
#pragma unroll
  for (int mm = 0; mm < 8; ++mm) { acc[mm] = __expf(acc[mm] - gm); ps += acc[mm]; }
  red[wv * 64 + lane] = ps;
  __syncthreads();
  float tot = 0.f;
#pragma unroll
  for (int w = 0; w < 8; ++w) tot += red[w * 64 + lane];
  float inv = 1.f / tot;

  const int gy = y0 + py, gx = x0 + px;
#pragma unroll
  for (int k = 0; k < 4; ++k) {
    int mp = (m0 >> 1) + k;
    att2[(size_t)mp * PL + (gy + 3) * WP + (gx + 3)] =
        pack2(acc[2 * k] * inv, acc[2 * k + 1] * inv);
  }
}

template<int P>
__device__ __forceinline__ void sim_core_tg(
    const unsigned* __restrict__ xt2, float* __restrict__ red,  // [8][8][64]
    const float* __restrict__ memT, unsigned* __restrict__ att2,
    int wv, int lane, int x0, int y0)
{
  constexpr int TH = 8 + P - 1, SR = SimSR<P>::v;
  constexpr int M = 8;
  const int px = lane & 7, py = lane >> 3;
  const int cp = wv;
  v2f acc2[4];
#pragma unroll
  for (int mm = 0; mm < 4; ++mm) acc2[mm] = (v2f){0.f, 0.f};

#pragma unroll
  for (int i = 0; i < P; ++i) {
#pragma unroll
    for (int j = 0; j < P; ++j) {
      v2f vp = unpack2(xt2[(cp * TH + py + i) * SR + (px + j)]);
      const v2f* w0 = (const v2f*)(memT + (size_t)((((2 * cp) * P + i) * P + j)) * M);
      const v2f* w1 = (const v2f*)(memT + (size_t)((((2 * cp + 1) * P + i) * P + j)) * M);
      v2f v0 = {vp.x, vp.x}, v1 = {vp.y, vp.y};
#pragma unroll
      for (int mm = 0; mm < 4; ++mm) {
        acc2[mm] = __builtin_elementwise_fma(v0, w0[mm], acc2[mm]);
        acc2[mm] = __builtin_elementwise_fma(v1, w1[mm], acc2[mm]);
      }
    }
  }

#pragma unroll
  for (int mm = 0; mm < 4; ++mm) {
    red[(wv * 8 + 2 * mm) * 64 + lane]     = acc2[mm].x;
    red[(wv * 8 + 2 * mm + 1) * 64 + lane] = acc2[mm].y;
  }
  __syncthreads();

  float lg[8];
#pragma unroll
  for (int m = 0; m < 8; ++m) {
    float s = red[m * 64 + lane];
#pragma unroll
    for (int w = 1; w < 8; ++w) s += red[(w * 8 + m) * 64 + lane];
    lg[m] = s;
  }
  float gm = lg[0];
#pragma unroll
  for (int m = 1; m < 8; ++m) gm = fmaxf(gm, lg[m]);
  float tot = 0.f;
#pragma unroll
  for (int m = 0; m < 8; ++m) { lg[m] = __expf(lg[m] - gm); tot += lg[m]; }
  float inv = 1.f / tot;

  const int gy = y0 + py, gx = x0 + px;
  if (wv < 4)
    att2[(size_t)wv * PL + (gy + 3) * WP + (gx + 3)] =
        pack2(lg[2 * wv] * inv, lg[2 * wv + 1] * inv);
}

template<int P>
__global__ __launch_bounds__(512, 8) void k_sim(
    const unsigned* __restrict__ xpad2,
    const float* __restrict__ memTbg, const float* __restrict__ memTtg,
    unsigned* __restrict__ attbg2,   // [2][32] pair-planes
    unsigned* __restrict__ atttg2)   // [2][4]  pair-planes
{
  constexpr int PAD = P / 2, TH = 8 + P - 1, SR = SimSR<P>::v;
  __shared__ unsigned xt2[8 * TH * SR];
  __shared__ float red[8 * 8 * 64];

  const int tid = threadIdx.x;
  const int wv = __builtin_amdgcn_readfirstlane(tid >> 6);
  const int lane = tid & 63;
  const int x0 = blockIdx.x * 8, y0 = blockIdx.y * 8;
  const int z = blockIdx.z;
  const bool isbg = z < 2;
  const int b = z & 1;

  const unsigned* xp = xpad2 + (size_t)(z * 8) * PL;
  const int oy = y0 + 3 - PAD, ox = x0 + 3 - PAD;
  for (int t = tid; t < 8 * TH * TH; t += 512) {
    int cp = t / (TH * TH);
    int r = t - cp * (TH * TH);
    int ly = r / TH, lx = r - ly * TH;
    xt2[(cp * TH + ly) * SR + lx] = xp[(size_t)cp * PL + (oy + ly) * WP + ox + lx];
  }
  __syncthreads();

  if (isbg) sim_core_bg<P>(xt2, red, memTbg, attbg2 + (size_t)(b * 32) * PL, wv, lane, x0, y0);
  else      sim_core_tg<P>(xt2, red, memTtg, atttg2 + (size_t)(b * 4) * PL, wv, lane, x0, y0);
}

// ---------------------------------------------------------------------------
// Read conv (hybrid, R14 form — best measured): 16x16 tile, 1 thread = 1
// pixel, fp32 inner loop (no unpack per FMA); f16 traffic at both ends —
// staging unpacks f16 att pairs ONCE into fp32 LDS planes; stores pack f16
// partials. bg: 16 chunks of 4 m; tg: 8 m -> fp32 final.
// z: 0,1 tg b; 2..33 bg chunk=(z-2)>>1, b=(z-2)&1.  SR=24 conflict-free.
// ---------------------------------------------------------------------------
template<int P>
__global__ __launch_bounds__(256, 8) void k_read(
    const unsigned* __restrict__ attbg2,   // [2][32] pair-planes
    const unsigned* __restrict__ atttg2,   // [2][4]  pair-planes
    const float* __restrict__ memRbg, const float* __restrict__ memRtg,
    unsigned* __restrict__ pbg2,           // [16][2][8][HW] u32 (this scale)
    float* __restrict__ ftg)               // [2 b][CHW]       (this scale)
{
  constexpr int PAD = P / 2, TH = 16 + P - 1, SR = 24;
  __shared__ float atf[8 * TH * SR];       // fp32 planes (bg uses 4, tg 8)

  const int tid = threadIdx.x;
  const int x0 = blockIdx.x * 16, y0 = blockIdx.y * 16;
  const int z = blockIdx.z;
  const bool isbg = z >= 2;
  const int b = isbg ? ((z - 2) & 1) : z;
  const int chunk = isbg ? ((z - 2) >> 1) : 0;
  const int nmp = isbg ? 2 : 4;            // f16 pair-planes staged
  const int nml = 2 * nmp;                 // fp32 planes in LDS
  const int mbase = isbg ? chunk * 4 : 0;
  const unsigned* attp = isbg ? (attbg2 + (size_t)(b * 32 + chunk * 2) * PL)
                              : (atttg2 + (size_t)(b * 4) * PL);
  const float* memR = isbg ? memRbg : memRtg;

  // stage: read f16 pair, unpack once -> two fp32 LDS planes
  const int oy = y0 + 3 - PAD, ox = x0 + 3 - PAD;
  for (int t = tid; t < nmp * TH * TH; t += 256) {
    int mp = t / (TH * TH);
    int r = t - mp * (TH * TH);
    int ly = r / TH, lx = r - ly * TH;
    v2f v = unpack2(attp[(size_t)mp * PL + (oy + ly) * WP + ox + lx]);
    atf[((2 * mp) * TH + ly) * SR + lx]     = v.x;
    atf[((2 * mp + 1) * TH + ly) * SR + lx] = v.y;
  }
  __syncthreads();

  const int px = tid & 15, py = tid >> 4;
  v2f acc2[8];
#pragma unroll
  for (int c = 0; c < 8; ++c) acc2[c] = (v2f){0.f, 0.f};

  for (int ml = 0; ml < nml; ++ml) {
    const float* atm = atf + ml * TH * SR;
    const float* wbase = memR + (size_t)((mbase + ml) * P * P) * C_CH;
#pragma unroll
    for (int u = 0; u < P; ++u) {
      const float* ar = atm + (py + u) * SR + px;
#pragma unroll
      for (int v2_ = 0; v2_ < P; ++v2_) {
        float val = ar[v2_];
        const v2f* wr = (const v2f*)(wbase + (u * P + v2_) * C_CH);
        v2f vv = {val, val};
#pragma unroll
        for (int c = 0; c < 8; ++c)
          acc2[c] = __builtin_elementwise_fma(vv, wr[c], acc2[c]);
      }
    }
  }

  const int gy = y0 + py, gx = x0 + px;
  int cy = min(P - 1, gy + PAD) - max(0, gy + PAD - (Hdim - 1)) + 1;
  int cx = min(P - 1, gx + PAD) - max(0, gx + PAD - (Wdim - 1)) + 1;
  float inv = 1.f / ((float)(cy * cx) + 1e-8f);
  if (isbg) {
    unsigned* outp = pbg2 + (size_t)((chunk * 2 + b) * 8) * HWdim + gy * Wdim + gx;
#pragma unroll
    for (int c = 0; c < 8; ++c)
      outp[(size_t)c * HWdim] = pack2(acc2[c].x * inv, acc2[c].y * inv);
  } else {
    float* outp = ftg + (size_t)b * CHW + gy * Wdim + gx;
#pragma unroll
    for (int c = 0; c < 8; ++c) {
      outp[(size_t)(2 * c) * HWdim]     = acc2[c].x * inv;
      outp[(size_t)(2 * c + 1) * HWdim] = acc2[c].y * inv;
    }
  }
}

// ---------------------------------------------------------------------------
// Sum f16 partial slabs -> final fbg (f32); fused pooled-mean (bg + tg).
// ---------------------------------------------------------------------------
__global__ __launch_bounds__(256) void k_sum(const unsigned* __restrict__ pbg2,
                                             const float* __restrict__ ftg,
                                             float* __restrict__ fbg,
                                             float* __restrict__ pooled)
{
  __shared__ float red[2][256];
  int bid = blockIdx.x;
  if (bid < 192) {
    int s = bid / 64;
    int rr = bid - s * 64;
    int b = rr >> 5;
    int cp = (rr >> 2) & 7;
    int q = rr & 3;
    size_t base = ((((size_t)(s * 16) * 2 + b) * 8) + cp) * HWdim + q * 4096;
    float* f0 = fbg + (size_t)(s * 2 + b) * CHW + (size_t)(2 * cp) * HWdim + q * 4096;
    float* f1 = f0 + HWdim;
    v2f ls = {0.f, 0.f};
    for (int t = threadIdx.x; t < 4096; t += 256) {
      v2f v = {0.f, 0.f};
#pragma unroll
      for (int ch = 0; ch < 16; ++ch)
        v += unpack2(pbg2[base + (size_t)ch * 16 * HWdim + t]);
      f0[t] = v.x;
      f1[t] = v.y;
      ls += v;
    }
    red[0][threadIdx.x] = ls.x;
    red[1][threadIdx.x] = ls.y;
    __syncthreads();
    for (int off = 128; off > 0; off >>= 1) {
      if ((int)threadIdx.x < off) {
        red[0][threadIdx.x] += red[0][threadIdx.x + off];
        red[1][threadIdx.x] += red[1][threadIdx.x + off];
      }
      __syncthreads();
    }
    if (threadIdx.x == 0) {
      gadd(&pooled[b * 16 + 2 * cp],     red[0][0] * (1.0f / (float)HWdim));
      gadd(&pooled[b * 16 + 2 * cp + 1], red[1][0] * (1.0f / (float)HWdim));
    }
  } else {
    int r = bid - 192;
    int s = r >> 7;
    int rr = r & 127;
    int b = rr >> 6;
    int c = (rr >> 2) & 15;
    int q = rr & 3;
    const float* f0 = ftg + (size_t)(s * 2 + b) * CHW + (size_t)c * HWdim + q * 4096;
    float ls = 0.f;
    for (int t = threadIdx.x; t < 4096; t += 256) ls += f0[t];
    red[0][threadIdx.x] = ls;
    __syncthreads();
    for (int off = 128; off > 0; off >>= 1) {
      if ((int)threadIdx.x < off) red[0][threadIdx.x] += red[0][threadIdx.x + off];
      __syncthreads();
    }
    if (threadIdx.x == 0)
      gadd(&pooled[32 + b * 16 + c], red[0][0] * (1.0f / (float)HWdim));
  }
}

// ---------------------------------------------------------------------------
// Fusion MLP + softmax weights
// ---------------------------------------------------------------------------
__global__ __launch_bounds__(128) void k_mlp(
    const float* __restrict__ pooled,
    const float* __restrict__ w1b, const float* __restrict__ b1b,
    const float* __restrict__ w2b, const float* __restrict__ b2b,
    const float* __restrict__ w1t, const float* __restrict__ b1t,
    const float* __restrict__ w2t, const float* __restrict__ b2t,
    float* __restrict__ wt)
{
  __shared__ float hdn[Bdim][4];
  __shared__ float lg[Bdim][48];
  int t = threadIdx.x;
  for (int br = 0; br < 2; ++br) {
    const float* w1 = br ? w1t : w1b;
    const float* b1 = br ? b1t : b1b;
    const float* w2 = br ? w2t : w2b;
    const float* b2 = br ? b2t : b2b;
    if (t < 8) {
      int b = t >> 2, h = t & 3;
      float s = b1[h];
      for (int c = 0; c < C_CH; ++c) s += pooled[br * 32 + b * 16 + c] * w1[h * 16 + c];
      hdn[b][h] = fmaxf(s, 0.f);
    }
    __syncthreads();
    if (t < 96) {
      int b = t / 48, j = t - b * 48;
      float s = b2[j];
      for (int h = 0; h < 4; ++h) s += hdn[b][h] * w2[j * 4 + h];
      lg[b][j] = s;
    }
    __syncthreads();
    if (t < 32) {
      int b = t >> 4, c = t & 15;
      float l0 = lg[b][c], l1 = lg[b][16 + c], l2 = lg[b][32 + c];
      float m = fmaxf(l0, fmaxf(l1, l2));
      float e0 = __expf(l0 - m), e1 = __expf(l1 - m), e2 = __expf(l2 - m);
      float inv = 1.f / (e0 + e1 + e2);
      wt[((br * 2 + b) * 3 + 0) * 16 + c] = e0 * inv;
      wt[((br * 2 + b) * 3 + 1) * 16 + c] = e1 * inv;
      wt[((br * 2 + b) * 3 + 2) * 16 + c] = e2 * inv;
    }
    __syncthreads();
  }
}

__global__ __launch_bounds__(256) void k_out(const float* __restrict__ fbg,
                                             const float* __restrict__ ftg,
                                             const float* __restrict__ wt,
                                             float* __restrict__ out)
{
  int idx = blockIdx.x * 256 + threadIdx.x;      // 0 .. 2*PAIR_ELEMS-1
  int br  = idx >> 19;                           // PAIR_ELEMS == 2^19
  int rem = idx & ((1 << 19) - 1);               // [b][c][HW]
  int b   = rem >> 18;                           // CHW == 2^18
  int off = rem & ((1 << 18) - 1);               // [c][HW]
  int c   = off >> 14;
  const float* f = (br == 0) ? fbg : ftg;
  int wbase = (br * 2 + b) * 3;
  float acc = 0.f;
#pragma unroll
  for (int s = 0; s < 3; ++s) {
    float v = f[(size_t)(s * 2 + b) * CHW + off];
    acc = fmaf(wt[(wbase + s) * 16 + c], v, acc);
  }
  out[idx] = acc;
}

// ---------------------------------------------------------------------------
extern "C" void kernel_launch(void* const* d_in, const int* in_sizes, int n_in,
                              void* d_out, int out_size, void* d_ws, size_t ws_size,
                              hipStream_t stream)
{
  const float* bg = (const float*)d_in[0];
  const float* tg = (const float*)d_in[1];
  const float* bg_mem[3]  = {(const float*)d_in[2],  (const float*)d_in[6],  (const float*)d_in[10]};
  const float* tg_mem[3]  = {(const float*)d_in[3],  (const float*)d_in[7],  (const float*)d_in[11]};
  const float* bg_temp[3] = {(const float*)d_in[4],  (const float*)d_in[8],  (const float*)d_in[12]};
  const float* tg_temp[3] = {(const float*)d_in[5],  (const float*)d_in[9],  (const float*)d_in[13]};
  const float* bg_fc1_w = (const float*)d_in[14];
  const float* bg_fc1_b = (const float*)d_in[15];
  const float* bg_fc2_w = (const float*)d_in[16];
  const float* bg_fc2_b = (const float*)d_in[17];
  const float* tg_fc1_w = (const float*)d_in[18];
  const float* tg_fc1_b = (const float*)d_in[19];
  const float* tg_fc2_w = (const float*)d_in[20];
  const float* tg_fc2_b = (const float*)d_in[21];

  float* ws = (float*)d_ws;
  unsigned* xpad2  = (unsigned*)ws;                        // 32 * PL
  unsigned* att2   = xpad2 + (size_t)32 * PL;              // 72 * PL
  float*    pooled = (float*)(att2 + (size_t)72 * PL);     // 64
  float*    wt     = pooled + 64;                          // 192
  float*    memT   = wt + 192;                             // 95,616
  float*    memR   = memT + 95616;                         // 95,616
  unsigned* pbg2   = (unsigned*)(memR + 95616);            // 3*16*2*8*HW u32
  float*    ftg    = (float*)(pbg2 + (size_t)3 * 16 * 2 * 8 * HWdim);  // 6*CHW
  float*    fbg    = ftg + (size_t)6 * CHW;                // 6*CHW

  unsigned* attbg2 = att2;                                 // [2][32] pair-planes
  unsigned* atttg2 = att2 + (size_t)64 * PL;               // [2][4]  pair-planes

  // zero xpad2 + att2 (borders) + pooled in one shot
  hipMemsetAsync(xpad2, 0, ((size_t)104 * PL) * 4 + 64 * 4, stream);

  const int   Ms[6] = {64, 64, 64, 8, 8, 8};
  const int   Ps[6] = {3, 5, 7, 3, 5, 7};
  const float* mems[6]  = {bg_mem[0], bg_mem[1], bg_mem[2], tg_mem[0], tg_mem[1], tg_mem[2]};
  const float* temps[6] = {bg_temp[0], bg_temp[1], bg_temp[2], tg_temp[0], tg_temp[1], tg_temp[2]};
  float* memTs[6]; float* memRs[6];
  PrepArgs pa;
  size_t off = 0;
  for (int k = 0; k < 6; ++k) {
    int D = C_CH * Ps[k] * Ps[k];
    memTs[k] = memT + off;
    memRs[k] = memR + off;
    pa.d[k] = {mems[k], temps[k], memTs[k], memRs[k], Ms[k], D, Ps[k]};
    off += (size_t)Ms[k] * D;
  }
  k_prep<<<dim3(196, 6), 256, 0, stream>>>(pa);
  k_padx<<<2048, 256, 0, stream>>>(bg, tg, xpad2);

  dim3 gs(16, 16, 4), bs(512);
  dim3 gr(8, 8, 34), brd(256);

  k_sim<3><<<gs, bs, 0, stream>>>(xpad2, memTs[0], memTs[3], attbg2, atttg2);
  k_read<3><<<gr, brd, 0, stream>>>(attbg2, atttg2, memRs[0], memRs[3],
                                    pbg2 + (size_t)0 * 16 * 2 * 8 * HWdim,
                                    ftg + (size_t)0 * 2 * CHW);
  k_sim<5><<<gs, bs, 0, stream>>>(xpad2, memTs[1], memTs[4], attbg2, atttg2);
  k_read<5><<<gr, brd, 0, stream>>>(attbg2, atttg2, memRs[1], memRs[4],
                                    pbg2 + (size_t)1 * 16 * 2 * 8 * HWdim,
                                    ftg + (size_t)1 * 2 * CHW);
  k_sim<7><<<gs, bs, 0, stream>>>(xpad2, memTs[2], memTs[5], attbg2, atttg2);
  k_read<7><<<gr, brd, 0, stream>>>(attbg2, atttg2, memRs[2], memRs[5],
                                    pbg2 + (size_t)2 * 16 * 2 * 8 * HWdim,
                                    ftg + (size_t)2 * 2 * CHW);

  k_sum<<<576, 256, 0, stream>>>(pbg2, ftg, fbg, pooled);
  k_mlp<<<1, 128, 0, stream>>>(pooled, bg_fc1_w, bg_fc1_b, bg_fc2_w, bg_fc2_b,
                               tg_fc1_w, tg_fc1_b, tg_fc2_w, tg_fc2_b, wt);
  k_out<<<(2 * PAIR_ELEMS) / 256, 256, 0, stream>>>(fbg, ftg, wt, (float*)d_out);
}